// Round 14
// baseline (9000.500 us; speedup 1.0000x reference)
//
#include <hip/hip_runtime.h>
#include <stdint.h>

#define BSZ  128
#define TLEN 8192
#define MDIM 64
#define SDIM 512
#define NEG_BIG (-1e30f)
#define QA   127   // signed-i8-safe quantization range (bytes in [0,127])

typedef int i32x4 __attribute__((ext_vector_type(4)));

// ---- 8-bit dot product: 4 MACs per instruction, exact i32 accumulation ----
#if __has_builtin(__builtin_amdgcn_udot4)
  __device__ __forceinline__ int dot4(unsigned a, unsigned b, int c) {
    return (int)__builtin_amdgcn_udot4(a, b, (unsigned)c, false);
  }
#elif __has_builtin(__builtin_amdgcn_sdot4)
  __device__ __forceinline__ int dot4(unsigned a, unsigned b, int c) {
    return __builtin_amdgcn_sdot4((int)a, (int)b, c, false);
  }
#else
  __device__ __forceinline__ int dot4(unsigned a, unsigned b, int c) {
    c += (int)((a & 0xffu) * (b & 0xffu));
    c += (int)(((a >> 8) & 0xffu) * ((b >> 8) & 0xffu));
    c += (int)(((a >> 16) & 0xffu) * ((b >> 16) & 0xffu));
    c += (int)((a >> 24) * (b >> 24));
    return c;
  }
#endif

// Wave-wide (64-lane) max via DPP, no LDS. Verified R3-R13 (absmax 0).
__device__ __forceinline__ float wave_max_f32(float x) {
  int v = __builtin_bit_cast(int, x);
#define DPP_STEP(ctrl)                                                        \
  {                                                                           \
    int o = __builtin_amdgcn_update_dpp(v, v, ctrl, 0xf, 0xf, false);         \
    v = __builtin_bit_cast(int, fmaxf(__builtin_bit_cast(float, v),           \
                                      __builtin_bit_cast(float, o)));         \
  }
  DPP_STEP(0x111)  // row_shr:1
  DPP_STEP(0x112)  // row_shr:2
  DPP_STEP(0x114)  // row_shr:4
  DPP_STEP(0x118)  // row_shr:8
  DPP_STEP(0x142)  // row_bcast15
  DPP_STEP(0x143)  // row_bcast31 -> lane63 has max(0..63)
#undef DPP_STEP
  return __builtin_bit_cast(float, __builtin_amdgcn_readlane(v, 63));
}

// Extract symbol index from one-hot rows: sym[b,t] = argmax_m x[b,t,m]
__global__ void sym_kernel(const float* __restrict__ x, uint8_t* __restrict__ sym) {
  int i = blockIdx.x * blockDim.x + threadIdx.x;  // flat (b,t)
  const float4* p = (const float4*)(x + (size_t)i * MDIM);
  int idx = 0;
  #pragma unroll
  for (int j = 0; j < 16; ++j) {
    float4 v = p[j];
    if (v.x > 0.5f) idx = 4*j + 0;
    if (v.y > 0.5f) idx = 4*j + 1;
    if (v.z > 0.5f) idx = 4*j + 2;
    if (v.w > 0.5f) idx = 4*j + 3;
  }
  sym[i] = (uint8_t)idx;
}

// Per-column max of A (quantization scale). One 64-thread block per column.
__global__ void colmax_kernel(const float* __restrict__ A, float* __restrict__ cmax) {
  int c = blockIdx.x, l = threadIdx.x;
  float m = 0.f;
  for (int r = l; r < SDIM; r += 64) m = fmaxf(m, A[(size_t)r * SDIM + c]);
  #pragma unroll
  for (int off = 32; off; off >>= 1) m = fmaxf(m, __shfl_xor(m, off));
  if (l == 0) cmax[c] = m;
}

// Pack A column-major as u8 row-quads: Aq[c*128 + j] = A[4j..4j+3][c] scaled
__global__ void pack_kernel(const float* __restrict__ A, const float* __restrict__ cmax,
                            unsigned* __restrict__ Aq) {
  int id = blockIdx.x * 256 + threadIdx.x;   // 512*128 = 65536 ids
  int c = id >> 7, j = id & 127;
  float s = (float)QA / cmax[c];
  unsigned q = 0;
  #pragma unroll
  for (int bb = 0; bb < 4; ++bb) {
    float v = A[(size_t)(4 * j + bb) * SDIM + c];
    int qi = (int)(v * s + 0.5f);
    if (qi > QA) qi = QA;
    q |= (unsigned)qi << (8 * bb);
  }
  Aq[c * 128 + j] = q;
}

// Linear-space scaled forward (R12 math, absmax 0). Hybrid compute:
// per wave, col-tiles 0-2 (48 cols) via MFMA (matrix pipe, 24 mfma), and
// the last 16 cols via v_dot4 on the VALU pipe (integer-identical result),
// with dot4's A streamed from L2 by 8 dwordx4 issued ~1300cy early.
// MFMA+VALU co-issue (m114) -> dot4 + A-stream hide under the MFMA phase,
// cutting the per-SIMD MFMA floor from ~1300 to ~980 cy.
__global__
#if __has_attribute(amdgpu_waves_per_eu)
__attribute__((amdgpu_waves_per_eu(2, 2)))
#endif
__launch_bounds__(512) void hmm_fwd(
    const unsigned* __restrict__ Aq, const float* __restrict__ cmax,
    const float* __restrict__ Bm, const uint8_t* __restrict__ sym,
    float* __restrict__ out) {
  const int b  = blockIdx.x;
  const int t  = threadIdx.x;        // == state owned
  const int wv = t >> 6;             // wave 0..7 -> cols 64wv..64wv+63
  const int ln = t & 63;
  const int pg = ln >> 4;            // K-subgroup / acc row-group

  __shared__ __align__(16) uint8_t p8[SDIM];   // quantized p
  __shared__ float red[8];                     // per-wave v maxes
  __shared__ float red2[8];

  // ---- MFMA B-operand tiles: col-tiles 0..2 x 8 K-tiles = 24 uint4 ----
  const uint4* aq4 = (const uint4*)Aq;
  const int cb = (wv << 6) + (ln & 15);        // this lane's base col
#define LDB(TT, KT) aq4[(size_t)(cb + 16 * TT) * 32 + KT * 4 + pg]
  uint4 B00=LDB(0,0),B01=LDB(0,1),B02=LDB(0,2),B03=LDB(0,3),
        B04=LDB(0,4),B05=LDB(0,5),B06=LDB(0,6),B07=LDB(0,7);
  uint4 B10=LDB(1,0),B11=LDB(1,1),B12=LDB(1,2),B13=LDB(1,3),
        B14=LDB(1,4),B15=LDB(1,5),B16=LDB(1,6),B17=LDB(1,7);
  uint4 B20=LDB(2,0),B21=LDB(2,1),B22=LDB(2,2),B23=LDB(2,3),
        B24=LDB(2,4),B25=LDB(2,5),B26=LDB(2,6),B27=LDB(2,7);
#undef LDB

  // dot4 duty: col dc = 64wv + 48 + (ln&15), rows pg*128 .. pg*128+127
  const uint4* dA = (const uint4*)(Aq + (size_t)((wv << 6) + 48 + (ln & 15)) * 128
                                   + (pg << 5));

  const float cscale = cmax[t] * (1.0f / ((float)QA * (float)QA));
  const uint8_t* symb = sym + (size_t)b * TLEN;

  // ---- init: v0 = exp(alpha0) = (B[s0,0]+eps) for t==0, else 0 ----
  int s0 = symb[0];
  float vReg = (t == 0) ? (Bm[s0 * SDIM + t] + 1e-16f) : 0.f;
  int   E_acc = 0;
  int   symNext = symb[1];
  float Ecur = Bm[symNext * SDIM + t] + 1e-16f;   // E_1 + eps
  symNext = symb[2];

  for (int step = 1; step < TLEN; ++step) {
    // ---- phase A: per-wave max -> red; issue dot4 A-stream + E early ----
    float m_w = wave_max_f32(vReg);
    if (ln == 0) red[wv] = m_w;
    uint4 A0 = dA[0], A1 = dA[1], A2 = dA[2], A3 = dA[3];   // L2 stream,
    uint4 A4 = dA[4], A5 = dA[5], A6 = dA[6], A7 = dA[7];   // lands in ~C
    float Enxt  = Bm[symNext * SDIM + t] + 1e-16f;
    int   symNN = (int)symb[(step + 2 <= TLEN - 1) ? step + 2 : TLEN - 1];
    __syncthreads();                  // B1: red ready

    // ---- phase B: global max -> pow2 scale -> quantize (no exp) ----
    float4 ra = *(const float4*)&red[0];
    float4 rb = *(const float4*)&red[4];
    float gm = fmaxf(fmaxf(fmaxf(ra.x, ra.y), fmaxf(ra.z, ra.w)),
                     fmaxf(fmaxf(rb.x, rb.y), fmaxf(rb.z, rb.w)));
    unsigned eb = (__builtin_bit_cast(unsigned, gm) >> 23) & 255u;
    float sqQ = __builtin_bit_cast(float, (253u - eb) << 23) * (float)QA;
    unsigned q = (unsigned)fmaf(vReg, sqQ, 0.5f);
    p8[t] = (uint8_t)q;
    __syncthreads();                  // B2: p8 ready

    // ---- phase C: MFMA (matrix pipe) + dot4 (vector pipe) co-issue ----
    const uint4* pq = (const uint4*)p8;
    uint4 P0 = pq[0*4+pg], P1 = pq[1*4+pg], P2 = pq[2*4+pg], P3 = pq[3*4+pg];
    uint4 P4 = pq[4*4+pg], P5 = pq[5*4+pg], P6 = pq[6*4+pg], P7 = pq[7*4+pg];
    // dot4 p slice: rows pg*128..+127 = 8 uint4
    const uint4* pd = (const uint4*)(p8 + (pg << 7));
    uint4 D0 = pd[0], D1 = pd[1], D2 = pd[2], D3 = pd[3];
    uint4 D4 = pd[4], D5 = pd[5], D6 = pd[6], D7 = pd[7];

    i32x4 l0={0,0,0,0}, l1={0,0,0,0}, l2={0,0,0,0};
    i32x4 h0={0,0,0,0}, h1={0,0,0,0}, h2={0,0,0,0};
#define MF(P, B, C) C = __builtin_amdgcn_mfma_i32_16x16x64_i8(              \
        __builtin_bit_cast(i32x4, P), __builtin_bit_cast(i32x4, B), C, 0, 0, 0)
    // lo K-half first (tail-shrink), hi K-half second
    MF(P0, B00, l0); MF(P0, B10, l1); MF(P0, B20, l2);
    MF(P1, B01, l0); MF(P1, B11, l1); MF(P1, B21, l2);
    MF(P2, B02, l0); MF(P2, B12, l1); MF(P2, B22, l2);
    MF(P3, B03, l0); MF(P3, B13, l1); MF(P3, B23, l2);
    MF(P4, B04, h0); MF(P4, B14, h1); MF(P4, B24, h2);
    MF(P5, B05, h0); MF(P5, B15, h1); MF(P5, B25, h2);
    MF(P6, B06, h0); MF(P6, B16, h1); MF(P6, B26, h2);
    MF(P7, B07, h0); MF(P7, B17, h1); MF(P7, B27, h2);
#undef MF

    // dot4 partial for col 64wv+48+(ln&15), rows pg*128..+127 (VALU pipe)
    int d = 0;
#define DD(PV, AV)                                                            \
    d = dot4(PV.x, AV.x, d); d = dot4(PV.y, AV.y, d);                         \
    d = dot4(PV.z, AV.z, d); d = dot4(PV.w, AV.w, d);
    DD(D0, A0) DD(D1, A1) DD(D2, A2) DD(D3, A3)
    DD(D4, A4) DD(D5, A5) DD(D6, A6) DD(D7, A7)
#undef DD
    d += __shfl_xor(d, 16);
    d += __shfl_xor(d, 32);           // all 4 pg-lanes now hold the col sum

    // ---- extract own-column result ----
    int rlo = (pg == 0) ? l0.x : (pg == 1) ? l1.x : l2.x;
    int rhi = (pg == 0) ? h0.x : (pg == 1) ? h1.x : h2.x;
    int rv  = (pg == 3) ? d : (rlo + rhi);

    // ---- v-update, fully in-register (exact ref math in linear space) ----
    vReg  = fmaf((float)rv, cscale, 1e-16f) * Ecur;
    E_acc += (int)eb - 126;           // e+1, exact ledger
    Ecur  = Enxt;
    symNext = symNN;
  }

  // ---- outputs: alpha_T = log(v) + E_acc*ln2, then loglik ----
  float alphaReg = __logf(vReg) + (float)E_acc * 0.6931471805599453f;
  out[(size_t)b * SDIM + t] = alphaReg;

  float mx = wave_max_f32(alphaReg);
  if (ln == 0) red2[wv] = mx;
  __syncthreads();
  float mf = fmaxf(fmaxf(fmaxf(red2[0], red2[1]), fmaxf(red2[2], red2[3])),
                   fmaxf(fmaxf(red2[4], red2[5]), fmaxf(red2[6], red2[7])));

  float se = __expf(alphaReg - mf);
  #pragma unroll
  for (int off = 32; off; off >>= 1) se += __shfl_xor(se, off);
  __syncthreads();                    // red2 reads done before rewrite
  if (ln == 0) red2[wv] = se;
  __syncthreads();
  if (t == 0) {
    float tot = 0.f;
    #pragma unroll
    for (int k = 0; k < 8; ++k) tot += red2[k];
    out[(size_t)BSZ * SDIM + b] = __logf(tot + SDIM * 1e-16f) + mf;
  }
}

extern "C" void kernel_launch(void* const* d_in, const int* in_sizes, int n_in,
                              void* d_out, int out_size, void* d_ws, size_t ws_size,
                              hipStream_t stream) {
  const float* x  = (const float*)d_in[0];
  const float* A  = (const float*)d_in[1];
  const float* Bm = (const float*)d_in[2];
  float* out = (float*)d_out;

  uint8_t*  sym  = (uint8_t*)d_ws;                                  // 1 MB
  unsigned* Aq   = (unsigned*)((char*)d_ws + (1 << 20));            // 256 KB
  float*    cmax = (float*)((char*)d_ws + (1 << 20) + (256 << 10)); // 2 KB

  sym_kernel<<<(BSZ * TLEN) / 256, 256, 0, stream>>>(x, sym);
  colmax_kernel<<<SDIM, 64, 0, stream>>>(A, cmax);
  pack_kernel<<<(SDIM * 128) / 256, 256, 0, stream>>>(A, cmax, Aq);
  hmm_fwd<<<BSZ, 512, 0, stream>>>(Aq, cmax, Bm, sym, out);
}